// Round 7
// baseline (277.320 us; speedup 1.0000x reference)
//
#include <hip/hip_runtime.h>

#define N_NODES 100000
#define N_EDGES 1600000
#define NB      50
#define GSIZE   2000
#define FEAT    128
#define NC      10
#define NSB     400        // 50 graphs x 8 sub-buckets (250 dst-nodes each)
#define BCAP    5120       // per-sub-bucket capacity (mean 4000, sd ~63 -> 17 sigma)
#define CHUNK   8192       // edges per binA block (r13: 2048->8192, 4x denser segments)
#define NBLK_A  196        // ceil(E / CHUNK)

using short8 = __attribute__((ext_vector_type(8))) short;
using f32x4  = __attribute__((ext_vector_type(4))) float;

__device__ __forceinline__ unsigned bf16rnd(float f) {
    unsigned u = __float_as_uint(f);
    return (u + 0x7fffu + ((u >> 16) & 1u)) >> 16;   // RNE bf16 bits
}
__device__ __forceinline__ float blo(unsigned w) { return __uint_as_float(w << 16); }
__device__ __forceinline__ float bhi(unsigned w) { return __uint_as_float(w & 0xffff0000u); }

// async global->LDS, 16B per lane. LDS dest must be wave-uniform base (+lane*16 implicit);
// global src is per-lane.
__device__ __forceinline__ void gload_lds16(const void* g, void* l) {
    __builtin_amdgcn_global_load_lds(
        (const __attribute__((address_space(1))) unsigned int*)g,
        (__attribute__((address_space(3))) unsigned int*)l, 16, 0, 0);
}

// XCD-pinned graph mapping: assumes XCD = blockIdx % 8 round-robin.
// XCD k owns graphs {k, k+8, ..., k+40} plus graph 48 (k=0) / 49 (k=1).
__device__ __forceinline__ int graph_of(int k, int gi) {
    if (gi < 6) return k + 8 * gi;
    return (k < 2) ? (48 + k) : -1;
}

// ---------------- phase A: bin edges into 400 sub-buckets + fused packW ------------
// r13 (theory: old scatter wrote ~5 words per 400 segments per block -> ~313K partial
// 64B lines = ~25MB RMW HBM traffic for a 6.4MB payload + 782-deep atomic contention
// on 400 addresses):
//   CHUNK=8192 (196 blocks): runs ~20 words (~82B) -> ~64% line utilization; atomic
//   depth 4x lower. Two-pass reload (count dst-only; re-read dst+src L2-warm and
//   place via LDS cursor atomics) keeps VGPRs low instead of holding 32 edges in
//   registers. Within-bucket order stays atomic-nondeterministic exactly as before.
//   packW fused at blockIdx >= NBLK_A (independent work; saves one launch).
__global__ __launch_bounds__(256) void k_binAW(
    const int* __restrict__ src, const int* __restrict__ dst,
    const float* __restrict__ W1, const float* __restrict__ W2,
    unsigned* __restrict__ gbuf, int* __restrict__ gcur,
    ushort* __restrict__ W1h, ushort* __restrict__ W1l,
    ushort* __restrict__ W2h, ushort* __restrict__ W2l) {
    if (blockIdx.x >= NBLK_A) {
        // ---- packW: W1+W2 (256x128 each) -> MFMA B-fragment layout, hi/lo ----
        int b = blockIdx.x - NBLK_A;             // 0..255; 128 blocks per W
        const float* W = (b < 128) ? W1 : W2;
        ushort* Wh = (b < 128) ? W1h : W2h;
        ushort* Wl = (b < 128) ? W1l : W2l;
        int idx = (b & 127) * 256 + threadIdx.x; // 0..32767
        int j = idx & 7, l = (idx >> 3) & 63, kb = (idx >> 9) & 7, c = idx >> 12;
        int k = kb * 32 + (l >> 4) * 8 + j;
        int col = c * 16 + (l & 15);
        float w = W[k * 128 + col];
        unsigned h = bf16rnd(w);
        float rem = w - __uint_as_float(h << 16);
        Wh[idx] = (ushort)h;
        Wl[idx] = (ushort)bf16rnd(rem);
        return;
    }
    __shared__ int cnt[NSB];      // count pass, then reused as placement cursor
    __shared__ int base[NSB];
    __shared__ int gbase[NSB];
    __shared__ int tsum[256];
    __shared__ unsigned stage[CHUNK];        // 32 KB
    __shared__ unsigned short bslot[CHUNK];  // 16 KB
    __shared__ int total_s;
    int tid = threadIdx.x;
    int e0 = blockIdx.x * CHUNK;
    for (int i = tid; i < NSB; i += 256) cnt[i] = 0;
    __syncthreads();

    // ---- round A: count (dst only) ----
#pragma unroll 4
    for (int q = 0; q < 32; ++q) {
        int e = e0 + q * 256 + tid;
        if (e < N_EDGES) {
            int d = dst[e];
            int g = d / 2000;                 // magic-mul
            int l = d - g * 2000;
            int sb = g * 8 + l / 250;         // magic-mul
            atomicAdd(&cnt[sb], 1);
        }
    }
    __syncthreads();
    // ---- parallel exclusive scan of cnt[400] (2 entries/thread + Hillis-Steele) ----
    int v0 = (2 * tid     < NSB) ? cnt[2 * tid]     : 0;
    int v1 = (2 * tid + 1 < NSB) ? cnt[2 * tid + 1] : 0;
    int loc = v0 + v1;
    tsum[tid] = loc; __syncthreads();
    for (int off = 1; off < 256; off <<= 1) {
        int t = (tid >= off) ? tsum[tid - off] : 0;
        __syncthreads(); tsum[tid] += t; __syncthreads();
    }
    int pref = tsum[tid] - loc;
    if (2 * tid     < NSB) base[2 * tid]     = pref;
    if (2 * tid + 1 < NSB) base[2 * tid + 1] = pref + v0;
    if (tid == 255) total_s = tsum[255];
    __syncthreads();
    // reserve global segments; reset cnt to serve as placement cursor
    for (int b = tid; b < NSB; b += 256) {
        int c = cnt[b];
        gbase[b] = atomicAdd(&gcur[b], c);
        cnt[b] = base[b];
    }
    __syncthreads();
    // ---- round B: re-read (L1/L2-warm) and place into LDS stage ----
#pragma unroll 4
    for (int q = 0; q < 32; ++q) {
        int e = e0 + q * 256 + tid;
        if (e < N_EDGES) {
            int d = dst[e];
            int g = d / 2000;
            int l = d - g * 2000;
            int sb = g * 8 + l / 250;
            int p = atomicAdd(&cnt[sb], 1);
            stage[p] = ((unsigned)src[e] << 11) | (unsigned)l;
            bslot[p] = (unsigned short)sb;
        }
    }
    __syncthreads();
    // ---- coalesced segmented write (runs ~20 words ≈ 82 B) ----
    int total = total_s;
    for (int s = tid; s < total; s += 256) {
        int b = bslot[s];
        gbuf[(size_t)b * BCAP + gbase[b] + (s - base[b])] = stage[s];
    }
}

// ---------------- fused per-sub-bucket prep + binB + convert -----------------------
// One block per sub-bucket (448 blocks): histogram + scan decompose exactly per
// sub-bucket; scatter fused (edge list L1-warm from histogram pass).
// convert phase fused too -- this block computed dinv for exactly the 250 nodes
// whose Yh rows convert produces (deletes k_convert launch + dinv round-trip).
__global__ __launch_bounds__(256) void k_prepB(
    const unsigned* __restrict__ gbuf, const int* __restrict__ gcur,
    const float* __restrict__ x,
    int* __restrict__ rowstart, float* __restrict__ dinv, float* __restrict__ sdeg,
    int* __restrict__ csrc, ushort* __restrict__ Yh) {
    __shared__ int hist[256];
    __shared__ int tsum[256];
    __shared__ int lcur[256];
    __shared__ float dvs[256];
    __shared__ int stage[BCAP];
    __shared__ int base_s;
    int B = blockIdx.x; int k = B & 7, j = B >> 3;
    int gi = j >> 3, q = j & 7;
    int g = graph_of(k, gi);
    if (g < 0) return;
    int tid = threadIdx.x;
    int sb = g * 8 + q;
    int n0l = q * 250;
    hist[tid] = 0;
    // base = sum gcur[0 .. sb) -- parallel reduce (<=2 loads/thread)
    int acc = 0;
    for (int i = tid; i < sb; i += 256) acc += gcur[i];
    tsum[tid] = acc;
    __syncthreads();
    for (int off = 128; off > 0; off >>= 1) {
        if (tid < off) tsum[tid] += tsum[tid + off];
        __syncthreads();
    }
    if (tid == 0) base_s = tsum[0];
    // 250-entry histogram over ~4000 edges (~16 iters)
    int nq = gcur[sb];
    const unsigned* bp = gbuf + (size_t)sb * BCAP;
    for (int i = tid; i < nq; i += 256)
        atomicAdd(&hist[(int)(bp[i] & 2047u) - n0l], 1);
    __syncthreads();
    int base = base_s;
    int v = hist[tid];
    tsum[tid] = v; __syncthreads();
    for (int off = 1; off < 256; off <<= 1) {
        int t = (tid >= off) ? tsum[tid - off] : 0;
        __syncthreads(); tsum[tid] += t; __syncthreads();
    }
    int pref = tsum[tid] - v;          // local exclusive prefix
    lcur[tid] = pref;
    if (tid < 250) {
        int node = g * GSIZE + n0l + tid;
        rowstart[node] = base + pref;
        float d = fmaxf((float)v, 1.f);
        float dv = rsqrtf(d);
        dinv[node] = dv;
        dvs[tid] = dv;
        sdeg[node] = sqrtf(d);
    }
    if (g == 49 && q == 7 && tid == 0) rowstart[N_NODES] = base + nq;
    __syncthreads();
    // scatter (bp is L1-warm from the histogram pass)
    for (int i = tid; i < nq; i += 256) {
        unsigned w = bp[i];
        int d = (int)(w & 2047u) - n0l;
        int p = atomicAdd(&lcur[d], 1);
        stage[p] = (int)(w >> 11);
    }
    __syncthreads();
    for (int s = tid; s < nq; s += 256)
        csrc[base + s] = stage[s];

    // ---- convert phase: Yh = bf16(dinv * x) for this block's 250 nodes ----
    const float4* x4 = (const float4*)x;
    uint2* Y2 = (uint2*)Yh;
    int nodebase = g * GSIZE + n0l;
#pragma unroll 4
    for (int idx = tid; idx < 250 * 32; idx += 256) {
        int r = idx >> 5, cc = idx & 31;
        float dv = dvs[r];
        float4 vx = x4[(size_t)(nodebase + r) * 32 + cc];
        uint2 yo;
        yo.x = bf16rnd(vx.x * dv) | (bf16rnd(vx.y * dv) << 16);
        yo.y = bf16rnd(vx.z * dv) | (bf16rnd(vx.w * dv) << 16);
        Y2[(size_t)(nodebase + r) * 32 + cc] = yo;
    }
}

// ---------------- gather: T[n] = bf16( -dinv[n] * sum_e Yh[csrc[e]] ) --------------
// XCD-pinned: 16 nodes/block, 16 lanes/node, 16B loads. Row = 16 uint4 (256 B).
// 4-edge software pipeline: 4 independent row-load/accumulate streams for MLP.
// Separate kernel (r10 lesson: fusing into gemm starved it of TLP).
// Predicated tail quad (tail loads issued in parallel, masked lanes zeroed).
__device__ __forceinline__ void acc8(float* a, uint4 u) {
    a[0] += blo(u.x); a[1] += bhi(u.x); a[2] += blo(u.y); a[3] += bhi(u.y);
    a[4] += blo(u.z); a[5] += bhi(u.z); a[6] += blo(u.w); a[7] += bhi(u.w);
}
__global__ __launch_bounds__(256) void k_gather(
    const ushort* __restrict__ Yh, const float* __restrict__ dinv,
    const int* __restrict__ rowstart, const int* __restrict__ csrc,
    ushort* __restrict__ Th) {
    int B = blockIdx.x; int k = B & 7, j = B >> 3;
    int gi = j / 125, local = j % 125;
    int g = graph_of(k, gi);
    if (g < 0) return;
    int tid = threadIdx.x;
    int c = tid & 15;          // 16B column group 0..15
    int i = tid >> 4;          // node 0..15
    int n = g * GSIZE + local * 16 + i;
    int rs = rowstart[n], re = rowstart[n + 1];
    float dn = -dinv[n];
    const uint4* Y4 = (const uint4*)Yh;
    float a0[8] = {0.f}, a1[8] = {0.f}, a2[8] = {0.f}, a3[8] = {0.f};
    int e = rs;
    for (; e + 3 < re; e += 4) {
        int s0 = csrc[e], s1 = csrc[e + 1], s2 = csrc[e + 2], s3 = csrc[e + 3];
        uint4 u0 = Y4[s0 * 16 + c];
        uint4 u1 = Y4[s1 * 16 + c];
        uint4 u2 = Y4[s2 * 16 + c];
        uint4 u3 = Y4[s3 * 16 + c];
        acc8(a0, u0); acc8(a1, u1); acc8(a2, u2); acc8(a3, u3);
    }
    if (e < re) {              // predicated tail quad (1-3 edges, loads in parallel)
        bool c1 = e + 1 < re, c2 = e + 2 < re;
        int s0 = csrc[e];
        int s1 = c1 ? csrc[e + 1] : s0;
        int s2 = c2 ? csrc[e + 2] : s0;
        uint4 u0 = Y4[s0 * 16 + c];
        uint4 u1 = Y4[s1 * 16 + c];
        uint4 u2 = Y4[s2 * 16 + c];
        if (!c1) { u1.x = 0u; u1.y = 0u; u1.z = 0u; u1.w = 0u; }
        if (!c2) { u2.x = 0u; u2.y = 0u; u2.z = 0u; u2.w = 0u; }
        acc8(a0, u0); acc8(a1, u1); acc8(a2, u2);
    }
#pragma unroll
    for (int t = 0; t < 8; ++t) a0[t] = (a0[t] + a1[t]) + (a2[t] + a3[t]);
    uint4 o;
    o.x = bf16rnd(a0[0] * dn) | (bf16rnd(a0[1] * dn) << 16);
    o.y = bf16rnd(a0[2] * dn) | (bf16rnd(a0[3] * dn) << 16);
    o.z = bf16rnd(a0[4] * dn) | (bf16rnd(a0[5] * dn) << 16);
    o.w = bf16rnd(a0[6] * dn) | (bf16rnd(a0[7] * dn) << 16);
    ((uint4*)Th)[n * 16 + c] = o;
}

// ---------------- MFMA GEMM (kb-outer / rt-inner) ----------------------------------
// out = relu(sdeg_row*(Y@Wa) + T@Wb + b).
// kb-outer / rt-inner nest: per kb-step only 4 W fragments (16 VGPR) live;
// accumulators accA[5]+accB[5] (40 VGPR, statically indexed, rt fully unrolled).
// Peak live set ~80 VGPR -> W resident by construction (r10 counter evidence:
// VGPR=56 meant asm-pinned W was spilled; structure, not pinning, controls this).
// A-tiles staged in LDS via global_load_lds, XOR-swizzled source (r7 win).
// mode 0: Oy = bf16(out * dinv[row]) -- MUST NOT alias Yh/Th.
// mode 1: fused segment-max into hg.
__global__ __launch_bounds__(256, 4) void k_gemm(
    const ushort* __restrict__ Yh, const ushort* __restrict__ Th,
    const ushort* __restrict__ Wh, const ushort* __restrict__ Wl,
    const float* __restrict__ bias, const float* __restrict__ dinv,
    const float* __restrict__ sdeg,
    ushort* __restrict__ Oy, float* __restrict__ hg, int mode) {
    __shared__ uint4 ldsY[1280];   // 80 rows x 16 chunks(16B) = 20KB
    __shared__ uint4 ldsT[1280];   // 20KB
    int B = blockIdx.x; int k = B & 7, j = B >> 3;
    int gi = j / 25, local = j % 25;
    int g = graph_of(k, gi);
    if (g < 0) return;
    int tid = threadIdx.x;
    int lane = tid & 63, wave = tid >> 6;
    int m = lane & 15, quad = lane >> 4;
    int rowbase = g * GSIZE + local * 80;

    // ---- stage A-tiles (XOR-swizzled global source, linear LDS dest) ----
    const uint4* Y4 = (const uint4*)Yh;
    const uint4* T4 = (const uint4*)Th;
#pragma unroll
    for (int it = 0; it < 5; ++it) {
        int ci = it * 256 + tid;
        int lr = ci >> 4, cc = ci & 15;
        int sc = cc ^ (lr & 7);
        size_t go = (size_t)(rowbase + lr) * 16 + sc;
        gload_lds16(Y4 + go, &ldsY[it * 256 + wave * 64]);   // wave-uniform dest
        gload_lds16(T4 + go, &ldsT[it * 256 + wave * 64]);
    }
    __syncthreads();   // drains vmcnt incl. global_load_lds

#pragma unroll 1
    for (int ci2 = 0; ci2 < 2; ++ci2) {
        int c = wave + ci2 * 4;
        int colc = c * 16 + m;
        float bb = bias[colc];

        f32x4 accA[5], accB[5];
#pragma unroll
        for (int rt = 0; rt < 5; ++rt) {
            accA[rt] = (f32x4){0.f, 0.f, 0.f, 0.f};
            accB[rt] = (f32x4){0.f, 0.f, 0.f, 0.f};
        }

#pragma unroll 1
        for (int kb = 0; kb < 4; ++kb) {
            int boA = ((c * 8 + kb) * 64 + lane) * 8;
            int boB = ((c * 8 + kb + 4) * 64 + lane) * 8;
            short8 whA = *reinterpret_cast<const short8*>(Wh + boA);
            short8 wlA = *reinterpret_cast<const short8*>(Wl + boA);
            short8 whB = *reinterpret_cast<const short8*>(Wh + boB);
            short8 wlB = *reinterpret_cast<const short8*>(Wl + boB);
            int qq = (kb * 4 + quad) ^ (m & 7);
#pragma unroll
            for (int rt = 0; rt < 5; ++rt) {
                int lr = rt * 16 + m;
                short8 aY = *reinterpret_cast<const short8*>(&ldsY[(lr << 4) | qq]);
                short8 aT = *reinterpret_cast<const short8*>(&ldsT[(lr << 4) | qq]);
                accA[rt] = __builtin_amdgcn_mfma_f32_16x16x32_bf16(aY, whA, accA[rt], 0, 0, 0);
                accA[rt] = __builtin_amdgcn_mfma_f32_16x16x32_bf16(aY, wlA, accA[rt], 0, 0, 0);
                accB[rt] = __builtin_amdgcn_mfma_f32_16x16x32_bf16(aT, whB, accB[rt], 0, 0, 0);
                accB[rt] = __builtin_amdgcn_mfma_f32_16x16x32_bf16(aT, wlB, accB[rt], 0, 0, 0);
            }
        }

        if (mode == 0) {
#pragma unroll
            for (int rt = 0; rt < 5; ++rt) {
#pragma unroll
                for (int r = 0; r < 4; ++r) {
                    int orow = rowbase + rt * 16 + quad * 4 + r;   // C/D: col=lane&15, row=quad*4+reg
                    float s = sdeg[orow], dv = dinv[orow];
                    float v = fmaxf(accA[rt][r] * s + accB[rt][r] + bb, 0.f);
                    Oy[orow * FEAT + colc] = (ushort)bf16rnd(v * dv);
                }
            }
        } else {
            float runc = 0.f;
#pragma unroll
            for (int rt = 0; rt < 5; ++rt) {
#pragma unroll
                for (int r = 0; r < 4; ++r) {
                    float s = sdeg[rowbase + rt * 16 + quad * 4 + r];
                    runc = fmaxf(runc, fmaxf(accA[rt][r] * s + accB[rt][r] + bb, 0.f));
                }
            }
            runc = fmaxf(runc, __shfl_xor(runc, 16));
            runc = fmaxf(runc, __shfl_xor(runc, 32));
            if (lane < 16) {
                atomicMax((int*)&hg[g * FEAT + colc], __float_as_int(runc));  // vals >= 0, hg 0-init
            }
        }
    }
}

// ---------------- classifier ----------------
__global__ void k_classify(const float* __restrict__ hg, const float* __restrict__ Wc,
                           const float* __restrict__ bc, float* __restrict__ out) {
    int g = blockIdx.x, t = threadIdx.x;
    if (t < NC) {
        float acc = bc[t];
        for (int j = 0; j < FEAT; ++j) acc += hg[g * FEAT + j] * Wc[j * NC + t];
        out[g * NC + t] = acc;
    }
}

extern "C" void kernel_launch(void* const* d_in, const int* in_sizes, int n_in,
                              void* d_out, int out_size, void* d_ws, size_t ws_size,
                              hipStream_t stream) {
    const float* x   = (const float*)d_in[0];
    const float* W1  = (const float*)d_in[1];
    const float* b1  = (const float*)d_in[2];
    const float* W2  = (const float*)d_in[3];
    const float* b2  = (const float*)d_in[4];
    const float* Wc  = (const float*)d_in[5];
    const float* bc  = (const float*)d_in[6];
    const int*   src = (const int*)d_in[7];
    const int*   dst = (const int*)d_in[8];
    float* out = (float*)d_out;

    char* ws = (char*)d_ws;
    size_t off = 0;
    auto alloc = [&](size_t bytes) { char* p = ws + off; off += (bytes + 255) & ~(size_t)255; return p; };
    int*      gcur     = (int*)     alloc(NSB * 4);           // contiguous with hg:
    float*    hg       = (float*)   alloc(NB * FEAT * 4);     // one memset covers both
    float*    dinv     = (float*)   alloc(N_NODES * 4);
    float*    sdeg     = (float*)   alloc(N_NODES * 4);
    int*      rowstart = (int*)     alloc((N_NODES + 1) * 4);
    unsigned* gbuf     = (unsigned*)alloc((size_t)NSB * BCAP * 4);
    int*      csrc     = (int*)     alloc((size_t)N_EDGES * 4);
    ushort*   W1h      = (ushort*)  alloc(256 * 128 * 2);
    ushort*   W1l      = (ushort*)  alloc(256 * 128 * 2);
    ushort*   W2h      = (ushort*)  alloc(256 * 128 * 2);
    ushort*   W2l      = (ushort*)  alloc(256 * 128 * 2);
    ushort*   Yh       = (ushort*)  alloc((size_t)N_NODES * FEAT * 2);  // dinv*x (layer-1 A)
    ushort*   Y2h      = (ushort*)  alloc((size_t)N_NODES * FEAT * 2);  // dinv*h (layer-2 A)
    ushort*   Th       = (ushort*)  alloc((size_t)N_NODES * FEAT * 2);  // T1 -> T2

    hipMemsetAsync(gcur, 0, 1792 + NB * FEAT * 4, stream);   // gcur(padded) + hg

    // CSR build (sub-bucketed counting sort; binA+packW fused; prep+scatter+convert fused)
    k_binAW<<<NBLK_A + 256, 256, 0, stream>>>(src, dst, W1, W2, gbuf, gcur,
                                              W1h, W1l, W2h, W2l);
    k_prepB<<<448, 256, 0, stream>>>(gbuf, gcur, x, rowstart, dinv, sdeg, csrc, Yh);

    // layer 1 (gemm writes dinv*h into Y2h -- distinct buffer, no intra-block race)
    k_gather<<<7000, 256, 0, stream>>>(Yh, dinv, rowstart, csrc, Th);
    k_gemm<<<1400, 256, 0, stream>>>(Yh, Th, W1h, W1l, b1, dinv, sdeg, Y2h, nullptr, 0);
    // layer 2 (fused segmax)
    k_gather<<<7000, 256, 0, stream>>>(Y2h, dinv, rowstart, csrc, Th);
    k_gemm<<<1400, 256, 0, stream>>>(Y2h, Th, W2h, W2l, b2, dinv, sdeg, nullptr, hg, 1);

    k_classify<<<NB, 64, 0, stream>>>(hg, Wc, bc, out);
}

// Round 8
// 265.163 us; speedup vs baseline: 1.0458x; 1.0458x over previous
//
#include <hip/hip_runtime.h>

#define N_NODES 100000
#define N_EDGES 1600000
#define NB      50
#define GSIZE   2000
#define FEAT    128
#define NC      10
#define NSB     400        // 50 graphs x 8 sub-buckets (250 dst-nodes each)
#define BCAP    5120       // per-sub-bucket capacity (mean 4000, sd ~63 -> 17 sigma)
#define CHUNK   2048       // edges per binA block (r14: reverted to 2048 -- measured best)
#define NBLK_A  782        // ceil(E / CHUNK)

using short8 = __attribute__((ext_vector_type(8))) short;
using f32x4  = __attribute__((ext_vector_type(4))) float;

__device__ __forceinline__ unsigned bf16rnd(float f) {
    unsigned u = __float_as_uint(f);
    return (u + 0x7fffu + ((u >> 16) & 1u)) >> 16;   // RNE bf16 bits
}
__device__ __forceinline__ float blo(unsigned w) { return __uint_as_float(w << 16); }
__device__ __forceinline__ float bhi(unsigned w) { return __uint_as_float(w & 0xffff0000u); }

// async global->LDS, 16B per lane. LDS dest must be wave-uniform base (+lane*16 implicit);
// global src is per-lane.
__device__ __forceinline__ void gload_lds16(const void* g, void* l) {
    __builtin_amdgcn_global_load_lds(
        (const __attribute__((address_space(1))) unsigned int*)g,
        (__attribute__((address_space(3))) unsigned int*)l, 16, 0, 0);
}

// XCD-pinned graph mapping: assumes XCD = blockIdx % 8 round-robin.
// XCD k owns graphs {k, k+8, ..., k+40} plus graph 48 (k=0) / 49 (k=1).
__device__ __forceinline__ int graph_of(int k, int gi) {
    if (gi < 6) return k + 8 * gi;
    return (k < 2) ? (48 + k) : -1;
}

// ---------------- phase A: bin edges into 400 sub-buckets (+ packW tail blocks) ----
// r14: EXACT round-5 binning (single-pass, 782 blocks -- measured best at 269us;
// r13's 8192-chunk two-pass variant measured 40-48us, occupancy 7.5%, latency-bound:
// trading TLP for write-traffic loses when nothing is near a roofline).
// packW's 256 independent blocks ride as a grid tail (blockIdx >= NBLK_A): saves one
// serial launch; both code paths byte-identical to their measured forms.
__global__ __launch_bounds__(256) void k_binA(
    const int* __restrict__ src, const int* __restrict__ dst,
    const float* __restrict__ W1, const float* __restrict__ W2,
    unsigned* __restrict__ gbuf, int* __restrict__ gcur,
    ushort* __restrict__ W1h, ushort* __restrict__ W1l,
    ushort* __restrict__ W2h, ushort* __restrict__ W2l) {
    if (blockIdx.x >= NBLK_A) {
        // ---- packW: W1+W2 (256x128 each) -> MFMA B-fragment layout, hi/lo ----
        int b = blockIdx.x - NBLK_A;             // 0..255; 128 blocks per W
        const float* W = (b < 128) ? W1 : W2;
        ushort* Wh = (b < 128) ? W1h : W2h;
        ushort* Wl = (b < 128) ? W1l : W2l;
        int idx = (b & 127) * 256 + threadIdx.x; // 0..32767
        int j = idx & 7, l = (idx >> 3) & 63, kb = (idx >> 9) & 7, c = idx >> 12;
        int k = kb * 32 + (l >> 4) * 8 + j;
        int col = c * 16 + (l & 15);
        float w = W[k * 128 + col];
        unsigned h = bf16rnd(w);
        float rem = w - __uint_as_float(h << 16);
        Wh[idx] = (ushort)h;
        Wl[idx] = (ushort)bf16rnd(rem);
        return;
    }
    __shared__ int cnt[NSB];
    __shared__ int base[NSB];
    __shared__ int gbase[NSB];
    __shared__ int tsum[256];
    __shared__ unsigned stage[CHUNK];
    __shared__ unsigned short bslot[CHUNK];
    __shared__ int total_s;
    int tid = threadIdx.x;
    int e0 = blockIdx.x * CHUNK;
    for (int i = tid; i < NSB; i += 256) cnt[i] = 0;
    __syncthreads();

    unsigned pv[8]; int pb[8], pr[8];
#pragma unroll
    for (int q = 0; q < 8; ++q) {
        int e = e0 + q * 256 + tid;
        pb[q] = -1;
        if (e < N_EDGES) {
            int d = dst[e];
            int g = d / 2000;                 // magic-mul
            int l = d - g * 2000;
            int sb = g * 8 + l / 250;         // magic-mul
            pv[q] = ((unsigned)src[e] << 11) | (unsigned)l;
            pb[q] = sb;
            pr[q] = atomicAdd(&cnt[sb], 1);
        }
    }
    __syncthreads();
    // parallel exclusive scan of cnt[400] (2 entries/thread + Hillis-Steele)
    int v0 = (2 * tid     < NSB) ? cnt[2 * tid]     : 0;
    int v1 = (2 * tid + 1 < NSB) ? cnt[2 * tid + 1] : 0;
    int loc = v0 + v1;
    tsum[tid] = loc; __syncthreads();
    for (int off = 1; off < 256; off <<= 1) {
        int t = (tid >= off) ? tsum[tid - off] : 0;
        __syncthreads(); tsum[tid] += t; __syncthreads();
    }
    int pref = tsum[tid] - loc;
    if (2 * tid     < NSB) base[2 * tid]     = pref;
    if (2 * tid + 1 < NSB) base[2 * tid + 1] = pref + v0;
    if (tid == 255) total_s = tsum[255];
    __syncthreads();
#pragma unroll
    for (int q = 0; q < 8; ++q) {
        if (pb[q] >= 0) {
            int s = base[pb[q]] + pr[q];
            stage[s] = pv[q];
            bslot[s] = (unsigned short)pb[q];
        }
    }
    for (int b = tid; b < NSB; b += 256) gbase[b] = atomicAdd(&gcur[b], cnt[b]);
    __syncthreads();
    int total = total_s;
    for (int s = tid; s < total; s += 256) {
        int b = bslot[s];
        gbuf[(size_t)b * BCAP + gbase[b] + (s - base[b])] = stage[s];
    }
}

// ---------------- fused per-sub-bucket prep + binB ---------------------------------
// One block per sub-bucket (448 blocks): histogram + scan decompose exactly per
// sub-bucket; scatter fused (edge list L1-warm from histogram pass).
__global__ __launch_bounds__(256) void k_prepB(
    const unsigned* __restrict__ gbuf, const int* __restrict__ gcur,
    int* __restrict__ rowstart, float* __restrict__ dinv, float* __restrict__ sdeg,
    int* __restrict__ csrc) {
    __shared__ int hist[256];
    __shared__ int tsum[256];
    __shared__ int lcur[256];
    __shared__ int stage[BCAP];
    __shared__ int base_s;
    int B = blockIdx.x; int k = B & 7, j = B >> 3;
    int gi = j >> 3, q = j & 7;
    int g = graph_of(k, gi);
    if (g < 0) return;
    int tid = threadIdx.x;
    int sb = g * 8 + q;
    int n0l = q * 250;
    hist[tid] = 0;
    // base = sum gcur[0 .. sb) -- parallel reduce (<=2 loads/thread)
    int acc = 0;
    for (int i = tid; i < sb; i += 256) acc += gcur[i];
    tsum[tid] = acc;
    __syncthreads();
    for (int off = 128; off > 0; off >>= 1) {
        if (tid < off) tsum[tid] += tsum[tid + off];
        __syncthreads();
    }
    if (tid == 0) base_s = tsum[0];
    // 250-entry histogram over ~4000 edges (~16 iters)
    int nq = gcur[sb];
    const unsigned* bp = gbuf + (size_t)sb * BCAP;
    for (int i = tid; i < nq; i += 256)
        atomicAdd(&hist[(int)(bp[i] & 2047u) - n0l], 1);
    __syncthreads();
    int base = base_s;
    int v = hist[tid];
    tsum[tid] = v; __syncthreads();
    for (int off = 1; off < 256; off <<= 1) {
        int t = (tid >= off) ? tsum[tid - off] : 0;
        __syncthreads(); tsum[tid] += t; __syncthreads();
    }
    int pref = tsum[tid] - v;          // local exclusive prefix
    lcur[tid] = pref;
    if (tid < 250) {
        int node = g * GSIZE + n0l + tid;
        rowstart[node] = base + pref;
        float d = fmaxf((float)v, 1.f);
        dinv[node] = rsqrtf(d);
        sdeg[node] = sqrtf(d);
    }
    if (g == 49 && q == 7 && tid == 0) rowstart[N_NODES] = base + nq;
    __syncthreads();
    // scatter (bp is L1-warm from the histogram pass)
    for (int i = tid; i < nq; i += 256) {
        unsigned w = bp[i];
        int d = (int)(w & 2047u) - n0l;
        int p = atomicAdd(&lcur[d], 1);
        stage[p] = (int)(w >> 11);
    }
    __syncthreads();
    for (int s = tid; s < nq; s += 256)
        csrc[base + s] = stage[s];
}

// ---------------- convert: Yh = bf16(dinv * x) (XCD-pinned per graph) --------------
__global__ __launch_bounds__(256) void k_convert(const float* __restrict__ x,
                          const float* __restrict__ dinv, ushort* __restrict__ Yh) {
    int B = blockIdx.x; int k = B & 7, j = B >> 3;
    int gi = j / 250, local = j % 250;
    int g = graph_of(k, gi);
    if (g < 0) return;
    int tid = threadIdx.x;
    int r = tid >> 5, c = tid & 31;
    int node = g * GSIZE + local * 8 + r;
    float dv = dinv[node];
    float4 v = ((const float4*)x)[node * 32 + c];
    uint2 yo;
    yo.x = bf16rnd(v.x * dv) | (bf16rnd(v.y * dv) << 16);
    yo.y = bf16rnd(v.z * dv) | (bf16rnd(v.w * dv) << 16);
    ((uint2*)Yh)[node * 32 + c] = yo;
}

// ---------------- gather: T[n] = bf16( -dinv[n] * sum_e Yh[csrc[e]] ) --------------
// XCD-pinned: 16 nodes/block, 16 lanes/node, 16B loads. Row = 16 uint4 (256 B).
// 4-edge software pipeline: 4 independent row-load/accumulate streams for MLP.
// Separate kernel (r10 lesson: fusing into gemm starved it of TLP).
__device__ __forceinline__ void acc8(float* a, uint4 u) {
    a[0] += blo(u.x); a[1] += bhi(u.x); a[2] += blo(u.y); a[3] += bhi(u.y);
    a[4] += blo(u.z); a[5] += bhi(u.z); a[6] += blo(u.w); a[7] += bhi(u.w);
}
__global__ __launch_bounds__(256) void k_gather(
    const ushort* __restrict__ Yh, const float* __restrict__ dinv,
    const int* __restrict__ rowstart, const int* __restrict__ csrc,
    ushort* __restrict__ Th) {
    int B = blockIdx.x; int k = B & 7, j = B >> 3;
    int gi = j / 125, local = j % 125;
    int g = graph_of(k, gi);
    if (g < 0) return;
    int tid = threadIdx.x;
    int c = tid & 15;          // 16B column group 0..15
    int i = tid >> 4;          // node 0..15
    int n = g * GSIZE + local * 16 + i;
    int rs = rowstart[n], re = rowstart[n + 1];
    const uint4* Y4 = (const uint4*)Yh;
    float a0[8] = {0.f}, a1[8] = {0.f}, a2[8] = {0.f}, a3[8] = {0.f};
    int e = rs;
    for (; e + 3 < re; e += 4) {
        int s0 = csrc[e], s1 = csrc[e + 1], s2 = csrc[e + 2], s3 = csrc[e + 3];
        uint4 u0 = Y4[s0 * 16 + c];
        uint4 u1 = Y4[s1 * 16 + c];
        uint4 u2 = Y4[s2 * 16 + c];
        uint4 u3 = Y4[s3 * 16 + c];
        acc8(a0, u0); acc8(a1, u1); acc8(a2, u2); acc8(a3, u3);
    }
    for (; e < re; ++e) {
        uint4 u = Y4[csrc[e] * 16 + c];
        acc8(a0, u);
    }
#pragma unroll
    for (int t = 0; t < 8; ++t) a0[t] = (a0[t] + a1[t]) + (a2[t] + a3[t]);
    float dn = -dinv[n];
    uint4 o;
    o.x = bf16rnd(a0[0] * dn) | (bf16rnd(a0[1] * dn) << 16);
    o.y = bf16rnd(a0[2] * dn) | (bf16rnd(a0[3] * dn) << 16);
    o.z = bf16rnd(a0[4] * dn) | (bf16rnd(a0[5] * dn) << 16);
    o.w = bf16rnd(a0[6] * dn) | (bf16rnd(a0[7] * dn) << 16);
    ((uint4*)Th)[n * 16 + c] = o;
}

// ---------------- MFMA GEMM (kb-outer / rt-inner) ----------------------------------
// out = relu(sdeg_row*(Y@Wa) + T@Wb + b).
// kb-outer / rt-inner nest: per kb-step only 4 W fragments (16 VGPR) live;
// accumulators accA[5]+accB[5] (40 VGPR, statically indexed, rt fully unrolled).
// Peak live set ~80 VGPR -> W resident by construction (r10 counter evidence:
// VGPR=56 meant asm-pinned W was spilled; structure, not pinning, controls this).
// A-tiles staged in LDS via global_load_lds, XOR-swizzled source (r7 win).
// mode 0: Oy = bf16(out * dinv[row]) -- MUST NOT alias Yh/Th.
// mode 1: fused segment-max into hg.
__global__ __launch_bounds__(256, 4) void k_gemm(
    const ushort* __restrict__ Yh, const ushort* __restrict__ Th,
    const ushort* __restrict__ Wh, const ushort* __restrict__ Wl,
    const float* __restrict__ bias, const float* __restrict__ dinv,
    const float* __restrict__ sdeg,
    ushort* __restrict__ Oy, float* __restrict__ hg, int mode) {
    __shared__ uint4 ldsY[1280];   // 80 rows x 16 chunks(16B) = 20KB
    __shared__ uint4 ldsT[1280];   // 20KB
    int B = blockIdx.x; int k = B & 7, j = B >> 3;
    int gi = j / 25, local = j % 25;
    int g = graph_of(k, gi);
    if (g < 0) return;
    int tid = threadIdx.x;
    int lane = tid & 63, wave = tid >> 6;
    int m = lane & 15, quad = lane >> 4;
    int rowbase = g * GSIZE + local * 80;

    // ---- stage A-tiles (XOR-swizzled global source, linear LDS dest) ----
    const uint4* Y4 = (const uint4*)Yh;
    const uint4* T4 = (const uint4*)Th;
#pragma unroll
    for (int it = 0; it < 5; ++it) {
        int ci = it * 256 + tid;
        int lr = ci >> 4, cc = ci & 15;
        int sc = cc ^ (lr & 7);
        size_t go = (size_t)(rowbase + lr) * 16 + sc;
        gload_lds16(Y4 + go, &ldsY[it * 256 + wave * 64]);   // wave-uniform dest
        gload_lds16(T4 + go, &ldsT[it * 256 + wave * 64]);
    }
    __syncthreads();   // drains vmcnt incl. global_load_lds

#pragma unroll 1
    for (int ci2 = 0; ci2 < 2; ++ci2) {
        int c = wave + ci2 * 4;
        int colc = c * 16 + m;
        float bb = bias[colc];

        f32x4 accA[5], accB[5];
#pragma unroll
        for (int rt = 0; rt < 5; ++rt) {
            accA[rt] = (f32x4){0.f, 0.f, 0.f, 0.f};
            accB[rt] = (f32x4){0.f, 0.f, 0.f, 0.f};
        }

#pragma unroll 1
        for (int kb = 0; kb < 4; ++kb) {
            int boA = ((c * 8 + kb) * 64 + lane) * 8;
            int boB = ((c * 8 + kb + 4) * 64 + lane) * 8;
            short8 whA = *reinterpret_cast<const short8*>(Wh + boA);
            short8 wlA = *reinterpret_cast<const short8*>(Wl + boA);
            short8 whB = *reinterpret_cast<const short8*>(Wh + boB);
            short8 wlB = *reinterpret_cast<const short8*>(Wl + boB);
            int qq = (kb * 4 + quad) ^ (m & 7);
#pragma unroll
            for (int rt = 0; rt < 5; ++rt) {
                int lr = rt * 16 + m;
                short8 aY = *reinterpret_cast<const short8*>(&ldsY[(lr << 4) | qq]);
                short8 aT = *reinterpret_cast<const short8*>(&ldsT[(lr << 4) | qq]);
                accA[rt] = __builtin_amdgcn_mfma_f32_16x16x32_bf16(aY, whA, accA[rt], 0, 0, 0);
                accA[rt] = __builtin_amdgcn_mfma_f32_16x16x32_bf16(aY, wlA, accA[rt], 0, 0, 0);
                accB[rt] = __builtin_amdgcn_mfma_f32_16x16x32_bf16(aT, whB, accB[rt], 0, 0, 0);
                accB[rt] = __builtin_amdgcn_mfma_f32_16x16x32_bf16(aT, wlB, accB[rt], 0, 0, 0);
            }
        }

        if (mode == 0) {
#pragma unroll
            for (int rt = 0; rt < 5; ++rt) {
#pragma unroll
                for (int r = 0; r < 4; ++r) {
                    int orow = rowbase + rt * 16 + quad * 4 + r;   // C/D: col=lane&15, row=quad*4+reg
                    float s = sdeg[orow], dv = dinv[orow];
                    float v = fmaxf(accA[rt][r] * s + accB[rt][r] + bb, 0.f);
                    Oy[orow * FEAT + colc] = (ushort)bf16rnd(v * dv);
                }
            }
        } else {
            float runc = 0.f;
#pragma unroll
            for (int rt = 0; rt < 5; ++rt) {
#pragma unroll
                for (int r = 0; r < 4; ++r) {
                    float s = sdeg[rowbase + rt * 16 + quad * 4 + r];
                    runc = fmaxf(runc, fmaxf(accA[rt][r] * s + accB[rt][r] + bb, 0.f));
                }
            }
            runc = fmaxf(runc, __shfl_xor(runc, 16));
            runc = fmaxf(runc, __shfl_xor(runc, 32));
            if (lane < 16) {
                atomicMax((int*)&hg[g * FEAT + colc], __float_as_int(runc));  // vals >= 0, hg 0-init
            }
        }
    }
}

// ---------------- classifier ----------------
__global__ void k_classify(const float* __restrict__ hg, const float* __restrict__ Wc,
                           const float* __restrict__ bc, float* __restrict__ out) {
    int g = blockIdx.x, t = threadIdx.x;
    if (t < NC) {
        float acc = bc[t];
        for (int j = 0; j < FEAT; ++j) acc += hg[g * FEAT + j] * Wc[j * NC + t];
        out[g * NC + t] = acc;
    }
}

extern "C" void kernel_launch(void* const* d_in, const int* in_sizes, int n_in,
                              void* d_out, int out_size, void* d_ws, size_t ws_size,
                              hipStream_t stream) {
    const float* x   = (const float*)d_in[0];
    const float* W1  = (const float*)d_in[1];
    const float* b1  = (const float*)d_in[2];
    const float* W2  = (const float*)d_in[3];
    const float* b2  = (const float*)d_in[4];
    const float* Wc  = (const float*)d_in[5];
    const float* bc  = (const float*)d_in[6];
    const int*   src = (const int*)d_in[7];
    const int*   dst = (const int*)d_in[8];
    float* out = (float*)d_out;

    char* ws = (char*)d_ws;
    size_t off = 0;
    auto alloc = [&](size_t bytes) { char* p = ws + off; off += (bytes + 255) & ~(size_t)255; return p; };
    int*      gcur     = (int*)     alloc(NSB * 4);           // contiguous with hg:
    float*    hg       = (float*)   alloc(NB * FEAT * 4);     // one memset covers both
    float*    dinv     = (float*)   alloc(N_NODES * 4);
    float*    sdeg     = (float*)   alloc(N_NODES * 4);
    int*      rowstart = (int*)     alloc((N_NODES + 1) * 4);
    unsigned* gbuf     = (unsigned*)alloc((size_t)NSB * BCAP * 4);
    int*      csrc     = (int*)     alloc((size_t)N_EDGES * 4);
    ushort*   W1h      = (ushort*)  alloc(256 * 128 * 2);
    ushort*   W1l      = (ushort*)  alloc(256 * 128 * 2);
    ushort*   W2h      = (ushort*)  alloc(256 * 128 * 2);
    ushort*   W2l      = (ushort*)  alloc(256 * 128 * 2);
    ushort*   Yh       = (ushort*)  alloc((size_t)N_NODES * FEAT * 2);  // dinv*x (layer-1 A)
    ushort*   Y2h      = (ushort*)  alloc((size_t)N_NODES * FEAT * 2);  // dinv*h (layer-2 A)
    ushort*   Th       = (ushort*)  alloc((size_t)N_NODES * FEAT * 2);  // T1 -> T2

    hipMemsetAsync(gcur, 0, 1792 + NB * FEAT * 4, stream);   // gcur(padded) + hg

    // CSR build (sub-bucketed counting sort; packW rides binA's grid tail)
    k_binA<<<NBLK_A + 256, 256, 0, stream>>>(src, dst, W1, W2, gbuf, gcur,
                                             W1h, W1l, W2h, W2l);
    k_prepB<<<448, 256, 0, stream>>>(gbuf, gcur, rowstart, dinv, sdeg, csrc);

    k_convert<<<14000, 256, 0, stream>>>(x, dinv, Yh);

    // layer 1 (gemm writes dinv*h into Y2h -- distinct buffer, no intra-block race)
    k_gather<<<7000, 256, 0, stream>>>(Yh, dinv, rowstart, csrc, Th);
    k_gemm<<<1400, 256, 0, stream>>>(Yh, Th, W1h, W1l, b1, dinv, sdeg, Y2h, nullptr, 0);
    // layer 2 (fused segmax)
    k_gather<<<7000, 256, 0, stream>>>(Y2h, dinv, rowstart, csrc, Th);
    k_gemm<<<1400, 256, 0, stream>>>(Y2h, Th, W2h, W2l, b2, dinv, sdeg, nullptr, hg, 1);

    k_classify<<<NB, 64, 0, stream>>>(hg, Wc, bc, out);
}